// Round 9
// baseline (101.083 us; speedup 1.0000x reference)
//
#include <hip/hip_runtime.h>

#define DIM    64      // CELL_DIM
#define NCELLS 512
#define ROWS_PER_BLOCK 32
#define NROWS  8192
#define NBLOCKS (NROWS / ROWS_PER_BLOCK)   // 256 = one block per CU
#define PCT_FLOATS (DIM * NCELLS)                  // 32768 fp32 = 128 KB
#define XT_FLOATS  (ROWS_PER_BLOCK * DIM)          // 2048 fp32 = 8 KB
#define LDS_BYTES  ((PCT_FLOATS + XT_FLOATS) * 4)  // 136 KB <= 160 KB/CU
#define REP    4

// R9 DIAGNOSTIC (deliberate, reverts next round): exact R7 structure, but the
// K-LOOP ONLY runs REP=4 times (staging/barrier/tail once). Purpose: R5/R8
// falsified the LDS-throughput model twice; must distinguish
//   (a) K-body ~10 us, latency-bound  -> pipeline the body next
//   (b) K-body ~7 us (VALU floor)     -> overlap staging / shrink tail next
// body_K = (dur_us - 72.0)/3; kernel (~45-52 us) also rises above the 41 us
// poison fills so top-5 finally shows VALUBusy/conflicts/VGPR for THIS
// structure. asm-sinks keep per-rep results live (rule #17). Final rep feeds
// the real output -> bit-identical results.
__global__ __launch_bounds__(1024, 4)
void placecells_kernel(const float* __restrict__ x,
                       const float* __restrict__ pc,
                       float* __restrict__ out)
{
    extern __shared__ float lds[];
    float* pcT = lds;                 // [64 k][512 cells], quad-swizzled
    float* xT  = lds + PCT_FLOATS;    // [32 rows][64 k], row-major

    const int tid = (int)threadIdx.x;
    const int l   = tid & 63;
    const int w   = __builtin_amdgcn_readfirstlane(tid >> 6);
    const int rowBase = (int)blockIdx.x * ROWS_PER_BLOCK + w * 2;

    // ---- stage x slice (8 KB), coalesced ----
    {
        float2 v = *(const float2*)(x + (size_t)blockIdx.x * ROWS_PER_BLOCK * DIM + 2 * tid);
        *(float2*)(&xT[2 * tid]) = v;
    }

    // ---- stage pc (128 KB): 8 loads issued first, then transpose-writes ----
    auto pc_ld = [&](int i) -> float4 {
        int idx = i * 1024 + tid;
        int cl  = idx >> 4;
        int kq  = idx & 15;
        return *(const float4*)(pc + cl * DIM + kq * 4);
    };
    auto pc_st = [&](int i, float4 v) {
        int idx = i * 1024 + tid;
        int cl  = idx >> 4;
        int kq  = idx & 15;
        int pq  = (cl >> 2) ^ kq;
        float* p = &pcT[(kq * 4) * NCELLS + pq * 4 + (cl & 3)];
        p[0 * NCELLS] = v.x;
        p[1 * NCELLS] = v.y;
        p[2 * NCELLS] = v.z;
        p[3 * NCELLS] = v.w;
    };
    float4 s0 = pc_ld(0), s1 = pc_ld(1), s2 = pc_ld(2), s3 = pc_ld(3);
    float4 s4 = pc_ld(4), s5 = pc_ld(5), s6 = pc_ld(6), s7 = pc_ld(7);
    pc_st(0, s0); pc_st(1, s1); pc_st(2, s2); pc_st(3, s3);
    pc_st(4, s4); pc_st(5, s5); pc_st(6, s6); pc_st(7, s7);

    __syncthreads();   // the ONLY barrier in the kernel

    float4 a0A{0,0,0,0}, a0B{0,0,0,0};
    float4 a1A{0,0,0,0}, a1B{0,0,0,0};

    const float* xr0 = &xT[(w * 2 + 0) * DIM];
    const float* xr1 = &xT[(w * 2 + 1) * DIM];

    // ---- K loop, repeated REP times (pcT/xT read-only after barrier) ----
    #pragma unroll 1
    for (int rep = 0; rep < REP; ++rep) {
        a0A = float4{0,0,0,0}; a0B = float4{0,0,0,0};
        a1A = float4{0,0,0,0}; a1B = float4{0,0,0,0};

        #pragma unroll
        for (int k4 = 0; k4 < 16; ++k4) {
            float4 xv0 = *(const float4*)(xr0 + k4 * 4);   // uniform ds_read
            float4 xv1 = *(const float4*)(xr1 + k4 * 4);
            const int pqA = (l ^ k4) * 4;     // undo swizzle: logical quad = l
            #pragma unroll
            for (int j = 0; j < 4; ++j) {
                const float* rowp = &pcT[(k4 * 4 + j) * NCELLS];
                float4 pvA = *(const float4*)(rowp + pqA);        // cells 4l..4l+3
                float4 pvB = *(const float4*)(rowp + pqA + 256);  // cells 256+4l..+3
                float x0 = (j == 0) ? xv0.x : (j == 1) ? xv0.y : (j == 2) ? xv0.z : xv0.w;
                float x1 = (j == 0) ? xv1.x : (j == 1) ? xv1.y : (j == 2) ? xv1.z : xv1.w;
                a0A.x += fabsf(x0 - pvA.x); a0A.y += fabsf(x0 - pvA.y);
                a0A.z += fabsf(x0 - pvA.z); a0A.w += fabsf(x0 - pvA.w);
                a0B.x += fabsf(x0 - pvB.x); a0B.y += fabsf(x0 - pvB.y);
                a0B.z += fabsf(x0 - pvB.z); a0B.w += fabsf(x0 - pvB.w);
                a1A.x += fabsf(x1 - pvA.x); a1A.y += fabsf(x1 - pvA.y);
                a1A.z += fabsf(x1 - pvA.z); a1A.w += fabsf(x1 - pvA.w);
                a1B.x += fabsf(x1 - pvB.x); a1B.y += fabsf(x1 - pvB.y);
                a1B.z += fabsf(x1 - pvB.z); a1B.w += fabsf(x1 - pvB.w);
            }
        }

        // keep this rep live so reps 0..REP-2 are not DCE'd (rule #17)
        asm volatile("" :: "v"(a0A.x), "v"(a0A.y), "v"(a0A.z), "v"(a0A.w),
                           "v"(a0B.x), "v"(a0B.y), "v"(a0B.z), "v"(a0B.w),
                           "v"(a1A.x), "v"(a1A.y), "v"(a1A.z), "v"(a1A.w),
                           "v"(a1B.x), "v"(a1B.y), "v"(a1B.z), "v"(a1B.w));
    }

    // ---- softmax tail: both rows interleaved (from final rep) ----
    {
        float mn0 = fminf(fminf(fminf(a0A.x, a0A.y), fminf(a0A.z, a0A.w)),
                          fminf(fminf(a0B.x, a0B.y), fminf(a0B.z, a0B.w)));
        float mn1 = fminf(fminf(fminf(a1A.x, a1A.y), fminf(a1A.z, a1A.w)),
                          fminf(fminf(a1B.x, a1B.y), fminf(a1B.z, a1B.w)));
        #pragma unroll
        for (int off = 32; off > 0; off >>= 1) {
            mn0 = fminf(mn0, __shfl_xor(mn0, off, 64));
            mn1 = fminf(mn1, __shfl_xor(mn1, off, 64));
        }
        float m20 = mn0 * mn0;
        float m21 = mn1 * mn1;

        float e00 = __expf(0.5f * (m20 - a0A.x * a0A.x));
        float e01 = __expf(0.5f * (m20 - a0A.y * a0A.y));
        float e02 = __expf(0.5f * (m20 - a0A.z * a0A.z));
        float e03 = __expf(0.5f * (m20 - a0A.w * a0A.w));
        float e04 = __expf(0.5f * (m20 - a0B.x * a0B.x));
        float e05 = __expf(0.5f * (m20 - a0B.y * a0B.y));
        float e06 = __expf(0.5f * (m20 - a0B.z * a0B.z));
        float e07 = __expf(0.5f * (m20 - a0B.w * a0B.w));
        float e10 = __expf(0.5f * (m21 - a1A.x * a1A.x));
        float e11 = __expf(0.5f * (m21 - a1A.y * a1A.y));
        float e12 = __expf(0.5f * (m21 - a1A.z * a1A.z));
        float e13 = __expf(0.5f * (m21 - a1A.w * a1A.w));
        float e14 = __expf(0.5f * (m21 - a1B.x * a1B.x));
        float e15 = __expf(0.5f * (m21 - a1B.y * a1B.y));
        float e16 = __expf(0.5f * (m21 - a1B.z * a1B.z));
        float e17 = __expf(0.5f * (m21 - a1B.w * a1B.w));

        float sum0 = ((e00 + e01) + (e02 + e03)) + ((e04 + e05) + (e06 + e07));
        float sum1 = ((e10 + e11) + (e12 + e13)) + ((e14 + e15) + (e16 + e17));
        #pragma unroll
        for (int off = 32; off > 0; off >>= 1) {
            sum0 += __shfl_xor(sum0, off, 64);
            sum1 += __shfl_xor(sum1, off, 64);
        }
        float inv0 = 1.0f / sum0;
        float inv1 = 1.0f / sum1;

        float* orow0 = out + (size_t)(rowBase + 0) * NCELLS;
        float* orow1 = out + (size_t)(rowBase + 1) * NCELLS;
        *(float4*)(orow0 + 4 * l)       = make_float4(e00 * inv0, e01 * inv0, e02 * inv0, e03 * inv0);
        *(float4*)(orow0 + 256 + 4 * l) = make_float4(e04 * inv0, e05 * inv0, e06 * inv0, e07 * inv0);
        *(float4*)(orow1 + 4 * l)       = make_float4(e10 * inv1, e11 * inv1, e12 * inv1, e13 * inv1);
        *(float4*)(orow1 + 256 + 4 * l) = make_float4(e14 * inv1, e15 * inv1, e16 * inv1, e17 * inv1);
    }
}

extern "C" void kernel_launch(void* const* d_in, const int* in_sizes, int n_in,
                              void* d_out, int out_size, void* d_ws, size_t ws_size,
                              hipStream_t stream)
{
    const float* x  = (const float*)d_in[0];   // (8192, 64) fp32
    const float* pc = (const float*)d_in[1];   // (512, 64) fp32
    float* out = (float*)d_out;                // (8192, 512) fp32
    placecells_kernel<<<dim3(NBLOCKS), dim3(1024), LDS_BYTES, stream>>>(x, pc, out);
}

// Round 10
// 73.488 us; speedup vs baseline: 1.3755x; 1.3755x over previous
//
#include <hip/hip_runtime.h>

#define DIM    64      // CELL_DIM
#define NCELLS 512
#define KHALF  32      // k staged per phase
#define ROWS_PER_BLOCK 16
#define NROWS  8192
#define NBLOCKS (NROWS / ROWS_PER_BLOCK)           // 512 blocks = 2 per CU
#define PCH_FLOATS (KHALF * NCELLS)                // 16384 fp32 = 64 KB
#define XT_FLOATS  (ROWS_PER_BLOCK * DIM)          // 1024 fp32 = 4 KB
#define LDS_BYTES  ((PCH_FLOATS + XT_FLOATS) * 4)  // 68 KB -> 2 blocks/CU

// R10: overlap the fixed costs. R9 measured: body 9.7 us (VALU-saturated, floor
// 6.8) but FIXED cost 14.7 us (staging ~5, tail drain ~3, ramp/barriers) fully
// EXPOSED at 1 block/CU. This version: 68 KB LDS -> 2 blocks/CU; block A's
// staging/tail/barriers hide under block B's compute. K split in halves with
// buffer reuse; h1 global loads issued before the first barrier into 32 held
// VGPRs (latency hides under h0 stage-wait + compute). Accumulation order per
// row is unchanged (k=0..63 sequential) -> bit-identical output.
// Geometry: 512 thr = 8 waves x 2 rows = 16 rows/block, 512 blocks, 3 barriers.
// Accumulators/staging regs are named float4s (R2 lesson: no runtime indexing).
__global__ __launch_bounds__(512, 4)
void placecells_kernel(const float* __restrict__ x,
                       const float* __restrict__ pc,
                       float* __restrict__ out)
{
    extern __shared__ float lds[];
    float* pcH = lds;                 // [32 k][512 cells], quad-swizzled, REUSED per half
    float* xT  = lds + PCH_FLOATS;    // [16 rows][64 k], row-major

    const int tid = (int)threadIdx.x;
    const int l   = tid & 63;
    const int w   = __builtin_amdgcn_readfirstlane(tid >> 6);
    const int rowBase = (int)blockIdx.x * ROWS_PER_BLOCK + w * 2;

    // ---- staging helpers: h, i compile-time at every call site ----
    auto pc_ld = [&](int h, int i) -> float4 {
        int idx = i * 512 + tid;                 // 0..4095
        int cl  = idx >> 3;                      // cell, 0..511
        int kq  = idx & 7;                       // local k-quad, 0..7
        return *(const float4*)(pc + cl * DIM + h * KHALF + kq * 4);
    };
    auto pc_st = [&](int h, int i, float4 v) {
        int idx = i * 512 + tid;
        int cl  = idx >> 3;
        int kq  = idx & 7;
        int k4g = h * 8 + kq;                    // global k-quad (swizzle key)
        int pq  = (cl >> 2) ^ k4g;               // quad swizzle (matches read)
        float* p = &pcH[(kq * 4) * NCELLS + pq * 4 + (cl & 3)];
        p[0 * NCELLS] = v.x;
        p[1 * NCELLS] = v.y;
        p[2 * NCELLS] = v.z;
        p[3 * NCELLS] = v.w;
    };

    // ---- phase 0: issue h0 loads, stage x, write h0, issue h1 loads ----
    float4 t0 = pc_ld(0,0), t1 = pc_ld(0,1), t2 = pc_ld(0,2), t3 = pc_ld(0,3);
    float4 t4 = pc_ld(0,4), t5 = pc_ld(0,5), t6 = pc_ld(0,6), t7 = pc_ld(0,7);
    {   // x slice: 1024 floats over 512 threads, coalesced
        float2 v = *(const float2*)(x + (size_t)blockIdx.x * ROWS_PER_BLOCK * DIM + 2 * tid);
        *(float2*)(&xT[2 * tid]) = v;
    }
    pc_st(0,0,t0); pc_st(0,1,t1); pc_st(0,2,t2); pc_st(0,3,t3);
    pc_st(0,4,t4); pc_st(0,5,t5); pc_st(0,6,t6); pc_st(0,7,t7);

    // h1 loads issued BEFORE the barrier: latency hides under h0 compute
    float4 u0 = pc_ld(1,0), u1 = pc_ld(1,1), u2 = pc_ld(1,2), u3 = pc_ld(1,3);
    float4 u4 = pc_ld(1,4), u5 = pc_ld(1,5), u6 = pc_ld(1,6), u7 = pc_ld(1,7);

    __syncthreads();   // barrier 1: h0 staged

    // a{row}{chunk}: 16 accumulator VGPRs
    float4 a0A{0,0,0,0}, a0B{0,0,0,0};
    float4 a1A{0,0,0,0}, a1B{0,0,0,0};

    const float* xr0 = &xT[(w * 2 + 0) * DIM];
    const float* xr1 = &xT[(w * 2 + 1) * DIM];

    // ---- compute one k-half: h compile-time at both call sites ----
    auto compute_half = [&](int h, float4& A0, float4& A1, float4& B0, float4& B1) {
        #pragma unroll
        for (int kq = 0; kq < 8; ++kq) {
            const int k4g = h * 8 + kq;
            float4 xv0 = *(const float4*)(xr0 + h * KHALF + kq * 4);  // uniform ds_read
            float4 xv1 = *(const float4*)(xr1 + h * KHALF + kq * 4);
            const int pqA = (l ^ k4g) * 4;    // undo swizzle: logical quad = l
            #pragma unroll
            for (int j = 0; j < 4; ++j) {
                const float* rowp = &pcH[(kq * 4 + j) * NCELLS];
                float4 pvA = *(const float4*)(rowp + pqA);        // cells 4l..4l+3
                float4 pvB = *(const float4*)(rowp + pqA + 256);  // cells 256+4l..+3
                float x0 = (j == 0) ? xv0.x : (j == 1) ? xv0.y : (j == 2) ? xv0.z : xv0.w;
                float x1 = (j == 0) ? xv1.x : (j == 1) ? xv1.y : (j == 2) ? xv1.z : xv1.w;
                A0.x += fabsf(x0 - pvA.x); A0.y += fabsf(x0 - pvA.y);
                A0.z += fabsf(x0 - pvA.z); A0.w += fabsf(x0 - pvA.w);
                B0.x += fabsf(x0 - pvB.x); B0.y += fabsf(x0 - pvB.y);
                B0.z += fabsf(x0 - pvB.z); B0.w += fabsf(x0 - pvB.w);
                A1.x += fabsf(x1 - pvA.x); A1.y += fabsf(x1 - pvA.y);
                A1.z += fabsf(x1 - pvA.z); A1.w += fabsf(x1 - pvA.w);
                B1.x += fabsf(x1 - pvB.x); B1.y += fabsf(x1 - pvB.y);
                B1.z += fabsf(x1 - pvB.z); B1.w += fabsf(x1 - pvB.w);
            }
        }
    };

    compute_half(0, a0A, a1A, a0B, a1B);

    __syncthreads();   // barrier 2: WAR — everyone done reading h0

    pc_st(1,0,u0); pc_st(1,1,u1); pc_st(1,2,u2); pc_st(1,3,u3);
    pc_st(1,4,u4); pc_st(1,5,u5); pc_st(1,6,u6); pc_st(1,7,u7);

    __syncthreads();   // barrier 3: h1 staged

    compute_half(1, a0A, a1A, a0B, a1B);

    // ---- softmax tail: both rows interleaved (independent dep chains) ----
    {
        float mn0 = fminf(fminf(fminf(a0A.x, a0A.y), fminf(a0A.z, a0A.w)),
                          fminf(fminf(a0B.x, a0B.y), fminf(a0B.z, a0B.w)));
        float mn1 = fminf(fminf(fminf(a1A.x, a1A.y), fminf(a1A.z, a1A.w)),
                          fminf(fminf(a1B.x, a1B.y), fminf(a1B.z, a1B.w)));
        #pragma unroll
        for (int off = 32; off > 0; off >>= 1) {
            mn0 = fminf(mn0, __shfl_xor(mn0, off, 64));
            mn1 = fminf(mn1, __shfl_xor(mn1, off, 64));
        }
        float m20 = mn0 * mn0;
        float m21 = mn1 * mn1;

        float e00 = __expf(0.5f * (m20 - a0A.x * a0A.x));
        float e01 = __expf(0.5f * (m20 - a0A.y * a0A.y));
        float e02 = __expf(0.5f * (m20 - a0A.z * a0A.z));
        float e03 = __expf(0.5f * (m20 - a0A.w * a0A.w));
        float e04 = __expf(0.5f * (m20 - a0B.x * a0B.x));
        float e05 = __expf(0.5f * (m20 - a0B.y * a0B.y));
        float e06 = __expf(0.5f * (m20 - a0B.z * a0B.z));
        float e07 = __expf(0.5f * (m20 - a0B.w * a0B.w));
        float e10 = __expf(0.5f * (m21 - a1A.x * a1A.x));
        float e11 = __expf(0.5f * (m21 - a1A.y * a1A.y));
        float e12 = __expf(0.5f * (m21 - a1A.z * a1A.z));
        float e13 = __expf(0.5f * (m21 - a1A.w * a1A.w));
        float e14 = __expf(0.5f * (m21 - a1B.x * a1B.x));
        float e15 = __expf(0.5f * (m21 - a1B.y * a1B.y));
        float e16 = __expf(0.5f * (m21 - a1B.z * a1B.z));
        float e17 = __expf(0.5f * (m21 - a1B.w * a1B.w));

        float sum0 = ((e00 + e01) + (e02 + e03)) + ((e04 + e05) + (e06 + e07));
        float sum1 = ((e10 + e11) + (e12 + e13)) + ((e14 + e15) + (e16 + e17));
        #pragma unroll
        for (int off = 32; off > 0; off >>= 1) {
            sum0 += __shfl_xor(sum0, off, 64);
            sum1 += __shfl_xor(sum1, off, 64);
        }
        float inv0 = 1.0f / sum0;
        float inv1 = 1.0f / sum1;

        float* orow0 = out + (size_t)(rowBase + 0) * NCELLS;
        float* orow1 = out + (size_t)(rowBase + 1) * NCELLS;
        *(float4*)(orow0 + 4 * l)       = make_float4(e00 * inv0, e01 * inv0, e02 * inv0, e03 * inv0);
        *(float4*)(orow0 + 256 + 4 * l) = make_float4(e04 * inv0, e05 * inv0, e06 * inv0, e07 * inv0);
        *(float4*)(orow1 + 4 * l)       = make_float4(e10 * inv1, e11 * inv1, e12 * inv1, e13 * inv1);
        *(float4*)(orow1 + 256 + 4 * l) = make_float4(e14 * inv1, e15 * inv1, e16 * inv1, e17 * inv1);
    }
}

extern "C" void kernel_launch(void* const* d_in, const int* in_sizes, int n_in,
                              void* d_out, int out_size, void* d_ws, size_t ws_size,
                              hipStream_t stream)
{
    const float* x  = (const float*)d_in[0];   // (8192, 64) fp32
    const float* pc = (const float*)d_in[1];   // (512, 64) fp32
    float* out = (float*)d_out;                // (8192, 512) fp32
    placecells_kernel<<<dim3(NBLOCKS), dim3(512), LDS_BYTES, stream>>>(x, pc, out);
}

// Round 11
// 72.638 us; speedup vs baseline: 1.3916x; 1.0117x over previous
//
#include <hip/hip_runtime.h>

#define DIM    64      // CELL_DIM
#define NCELLS 512
#define KHALF  32      // k per half
#define ROWS_PER_BLOCK 32
#define NROWS  8192
#define NBLOCKS (NROWS / ROWS_PER_BLOCK)           // 256 = one block per CU
#define PCH_FLOATS (KHALF * NCELLS)                // 16384 fp32 = 64 KB per half
#define XT_FLOATS  (ROWS_PER_BLOCK * DIM)          // 2048 fp32 = 8 KB
#define LDS_BYTES  ((2 * PCH_FLOATS + XT_FLOATS) * 4)  // 136 KB -> 1 block/CU

// R11: in-block double-buffered staging. R10 showed sibling-block overlap fails
// (co-launched blocks run phases in lockstep); this version overlaps
// STRUCTURALLY within one block: pc staged as two 64 KB K-halves in separate
// buffers; all global loads issued up front; h1's ds_writes are issued right
// after barrier 1 and retire on the LDS pipe UNDER h0's compute. Exposed
// staging = h0 prologue only. Geometry: 1024 thr = 16 waves x 2 rows,
// 1 block/CU, 2 barriers. Accumulation order k=0..63 per row unchanged ->
// bit-identical output. Named float4 temps/accs only (R2 scratch lesson).
__global__ __launch_bounds__(1024, 4)
void placecells_kernel(const float* __restrict__ x,
                       const float* __restrict__ pc,
                       float* __restrict__ out)
{
    extern __shared__ float lds[];
    float* pcH0 = lds;                      // [32 k][512 cells], quad-swizzled
    float* pcH1 = lds + PCH_FLOATS;         // [32 k][512 cells], quad-swizzled
    float* xT   = lds + 2 * PCH_FLOATS;     // [32 rows][64 k], row-major

    const int tid = (int)threadIdx.x;
    const int l   = tid & 63;
    const int w   = __builtin_amdgcn_readfirstlane(tid >> 6);
    const int rowBase = (int)blockIdx.x * ROWS_PER_BLOCK + w * 2;

    // ---- staging helpers: h, i compile-time at every call site ----
    // 4096 float4 per half over 1024 threads = 4 items/thread.
    auto pc_ld = [&](int h, int i) -> float4 {
        int idx = i * 1024 + tid;                // 0..4095
        int cl  = idx >> 3;                      // cell, 0..511
        int kq  = idx & 7;                       // local k-quad, 0..7
        return *(const float4*)(pc + cl * DIM + h * KHALF + kq * 4);
    };
    auto pc_st = [&](float* buf, int h, int i, float4 v) {
        int idx = i * 1024 + tid;
        int cl  = idx >> 3;
        int kq  = idx & 7;
        int k4g = h * 8 + kq;                    // global k-quad (swizzle key)
        int pq  = (cl >> 2) ^ k4g;               // quad swizzle (matches read)
        float* p = &buf[(kq * 4) * NCELLS + pq * 4 + (cl & 3)];
        p[0 * NCELLS] = v.x;
        p[1 * NCELLS] = v.y;
        p[2 * NCELLS] = v.z;
        p[3 * NCELLS] = v.w;
    };

    // ---- prologue: issue ALL global loads, then write x + h0 ----
    float4 t0 = pc_ld(0,0), t1 = pc_ld(0,1), t2 = pc_ld(0,2), t3 = pc_ld(0,3);
    float4 u0 = pc_ld(1,0), u1 = pc_ld(1,1), u2 = pc_ld(1,2), u3 = pc_ld(1,3);
    {   // x slice: 2048 floats over 1024 threads, coalesced
        float2 v = *(const float2*)(x + (size_t)blockIdx.x * ROWS_PER_BLOCK * DIM + 2 * tid);
        *(float2*)(&xT[2 * tid]) = v;
    }
    pc_st(pcH0, 0, 0, t0); pc_st(pcH0, 0, 1, t1);
    pc_st(pcH0, 0, 2, t2); pc_st(pcH0, 0, 3, t3);

    __syncthreads();   // barrier 1: h0 + x staged (vmcnt drained -> u0..u3 held)

    // h1 writes issued NOW: retire on LDS pipe underneath h0 compute
    pc_st(pcH1, 1, 0, u0); pc_st(pcH1, 1, 1, u1);
    pc_st(pcH1, 1, 2, u2); pc_st(pcH1, 1, 3, u3);

    // a{row}{chunk}: 16 accumulator VGPRs
    float4 a0A{0,0,0,0}, a0B{0,0,0,0};
    float4 a1A{0,0,0,0}, a1B{0,0,0,0};

    const float* xr0 = &xT[(w * 2 + 0) * DIM];
    const float* xr1 = &xT[(w * 2 + 1) * DIM];

    // ---- compute one k-half: buf/h compile-time at both call sites ----
    auto compute_half = [&](const float* buf, int h) {
        #pragma unroll
        for (int kq = 0; kq < 8; ++kq) {
            const int k4g = h * 8 + kq;
            float4 xv0 = *(const float4*)(xr0 + h * KHALF + kq * 4);  // uniform ds_read
            float4 xv1 = *(const float4*)(xr1 + h * KHALF + kq * 4);
            const int pqA = (l ^ k4g) * 4;    // undo swizzle: logical quad = l
            #pragma unroll
            for (int j = 0; j < 4; ++j) {
                const float* rowp = &buf[(kq * 4 + j) * NCELLS];
                float4 pvA = *(const float4*)(rowp + pqA);        // cells 4l..4l+3
                float4 pvB = *(const float4*)(rowp + pqA + 256);  // cells 256+4l..+3
                float x0 = (j == 0) ? xv0.x : (j == 1) ? xv0.y : (j == 2) ? xv0.z : xv0.w;
                float x1 = (j == 0) ? xv1.x : (j == 1) ? xv1.y : (j == 2) ? xv1.z : xv1.w;
                a0A.x += fabsf(x0 - pvA.x); a0A.y += fabsf(x0 - pvA.y);
                a0A.z += fabsf(x0 - pvA.z); a0A.w += fabsf(x0 - pvA.w);
                a0B.x += fabsf(x0 - pvB.x); a0B.y += fabsf(x0 - pvB.y);
                a0B.z += fabsf(x0 - pvB.z); a0B.w += fabsf(x0 - pvB.w);
                a1A.x += fabsf(x1 - pvA.x); a1A.y += fabsf(x1 - pvA.y);
                a1A.z += fabsf(x1 - pvA.z); a1A.w += fabsf(x1 - pvA.w);
                a1B.x += fabsf(x1 - pvB.x); a1B.y += fabsf(x1 - pvB.y);
                a1B.z += fabsf(x1 - pvB.z); a1B.w += fabsf(x1 - pvB.w);
            }
        }
    };

    compute_half(pcH0, 0);

    __syncthreads();   // barrier 2: h1 writes complete (lgkmcnt drained)

    compute_half(pcH1, 1);

    // ---- softmax tail: both rows interleaved (independent dep chains) ----
    {
        float mn0 = fminf(fminf(fminf(a0A.x, a0A.y), fminf(a0A.z, a0A.w)),
                          fminf(fminf(a0B.x, a0B.y), fminf(a0B.z, a0B.w)));
        float mn1 = fminf(fminf(fminf(a1A.x, a1A.y), fminf(a1A.z, a1A.w)),
                          fminf(fminf(a1B.x, a1B.y), fminf(a1B.z, a1B.w)));
        #pragma unroll
        for (int off = 32; off > 0; off >>= 1) {
            mn0 = fminf(mn0, __shfl_xor(mn0, off, 64));
            mn1 = fminf(mn1, __shfl_xor(mn1, off, 64));
        }
        float m20 = mn0 * mn0;
        float m21 = mn1 * mn1;

        float e00 = __expf(0.5f * (m20 - a0A.x * a0A.x));
        float e01 = __expf(0.5f * (m20 - a0A.y * a0A.y));
        float e02 = __expf(0.5f * (m20 - a0A.z * a0A.z));
        float e03 = __expf(0.5f * (m20 - a0A.w * a0A.w));
        float e04 = __expf(0.5f * (m20 - a0B.x * a0B.x));
        float e05 = __expf(0.5f * (m20 - a0B.y * a0B.y));
        float e06 = __expf(0.5f * (m20 - a0B.z * a0B.z));
        float e07 = __expf(0.5f * (m20 - a0B.w * a0B.w));
        float e10 = __expf(0.5f * (m21 - a1A.x * a1A.x));
        float e11 = __expf(0.5f * (m21 - a1A.y * a1A.y));
        float e12 = __expf(0.5f * (m21 - a1A.z * a1A.z));
        float e13 = __expf(0.5f * (m21 - a1A.w * a1A.w));
        float e14 = __expf(0.5f * (m21 - a1B.x * a1B.x));
        float e15 = __expf(0.5f * (m21 - a1B.y * a1B.y));
        float e16 = __expf(0.5f * (m21 - a1B.z * a1B.z));
        float e17 = __expf(0.5f * (m21 - a1B.w * a1B.w));

        float sum0 = ((e00 + e01) + (e02 + e03)) + ((e04 + e05) + (e06 + e07));
        float sum1 = ((e10 + e11) + (e12 + e13)) + ((e14 + e15) + (e16 + e17));
        #pragma unroll
        for (int off = 32; off > 0; off >>= 1) {
            sum0 += __shfl_xor(sum0, off, 64);
            sum1 += __shfl_xor(sum1, off, 64);
        }
        float inv0 = 1.0f / sum0;
        float inv1 = 1.0f / sum1;

        float* orow0 = out + (size_t)(rowBase + 0) * NCELLS;
        float* orow1 = out + (size_t)(rowBase + 1) * NCELLS;
        *(float4*)(orow0 + 4 * l)       = make_float4(e00 * inv0, e01 * inv0, e02 * inv0, e03 * inv0);
        *(float4*)(orow0 + 256 + 4 * l) = make_float4(e04 * inv0, e05 * inv0, e06 * inv0, e07 * inv0);
        *(float4*)(orow1 + 4 * l)       = make_float4(e10 * inv1, e11 * inv1, e12 * inv1, e13 * inv1);
        *(float4*)(orow1 + 256 + 4 * l) = make_float4(e14 * inv1, e15 * inv1, e16 * inv1, e17 * inv1);
    }
}

extern "C" void kernel_launch(void* const* d_in, const int* in_sizes, int n_in,
                              void* d_out, int out_size, void* d_ws, size_t ws_size,
                              hipStream_t stream)
{
    const float* x  = (const float*)d_in[0];   // (8192, 64) fp32
    const float* pc = (const float*)d_in[1];   // (512, 64) fp32
    float* out = (float*)d_out;                // (8192, 512) fp32
    placecells_kernel<<<dim3(NBLOCKS), dim3(1024), LDS_BYTES, stream>>>(x, pc, out);
}